// Round 2
// baseline (1374.794 us; speedup 1.0000x reference)
//
#include <hip/hip_runtime.h>

constexpr int FD = 128;
constexpr int NBMAX = 512;   // max coarse buckets (rows/128); n<=65536
constexpr int CH1 = 2048;    // edges per binning block

// ---- monotone float<->uint encoding for atomic max over floats ----
__device__ __forceinline__ unsigned fenc(float f) {
    unsigned u = __float_as_uint(f);
    return (u & 0x80000000u) ? ~u : (u | 0x80000000u);
}
__device__ __forceinline__ float fdec(unsigned e) {
    return (e & 0x80000000u) ? __uint_as_float(e & 0x7fffffffu)
                             : __uint_as_float(~e);
}

// ---- zero bucket histogram, init max slots ----
__global__ __launch_bounds__(512) void init_kernel(int* __restrict__ bhist,
                                                   unsigned* __restrict__ maxslot) {
    int t = threadIdx.x;
    bhist[t] = 0;                          // NBMAX entries
    if (t < 2) maxslot[t] = 0x007FFFFFu;   // fenc(-inf)
}

// ---- Wh = h @ W^T  (fp32 vector ALU; 16 rows/block, thread = one out column) ----
__global__ __launch_bounds__(256) void gemm_kernel(const float* __restrict__ h,
                                                   const float* __restrict__ W,
                                                   float* __restrict__ Wh, int n) {
    __shared__ float hs[16 * FD];  // 8 KB
    int tid = threadIdx.x;
    int rbase = blockIdx.x * 16;

    {
        const float4* h4 = (const float4*)(h + (size_t)rbase * FD);
        float4* hs4 = (float4*)hs;
        int r0 = rbase + (tid >> 5);
        int r1 = rbase + ((tid + 256) >> 5);
        hs4[tid]       = (r0 < n) ? h4[tid]       : make_float4(0.f, 0.f, 0.f, 0.f);
        hs4[tid + 256] = (r1 < n) ? h4[tid + 256] : make_float4(0.f, 0.f, 0.f, 0.f);
    }
    __syncthreads();

    int j = tid & 127;
    int g = tid >> 7;
    float acc[8] = {0.f, 0.f, 0.f, 0.f, 0.f, 0.f, 0.f, 0.f};
    const float4* W4 = (const float4*)(W + (size_t)j * FD);

#pragma unroll 4
    for (int k4 = 0; k4 < 32; ++k4) {
        float4 w = W4[k4];
#pragma unroll
        for (int rr = 0; rr < 8; ++rr) {
            float4 hv = ((const float4*)(hs + (g * 8 + rr) * FD))[k4];
            acc[rr] = fmaf(w.x, hv.x, acc[rr]);
            acc[rr] = fmaf(w.y, hv.y, acc[rr]);
            acc[rr] = fmaf(w.z, hv.z, acc[rr]);
            acc[rr] = fmaf(w.w, hv.w, acc[rr]);
        }
    }
#pragma unroll
    for (int rr = 0; rr < 8; ++rr) {
        int r = rbase + g * 8 + rr;
        if (r < n) Wh[(size_t)r * FD + j] = acc[rr];
    }
}

// ---- s1/s2 per row + global maxes of s1 and s2 (one wave per row) ----
__global__ __launch_bounds__(256) void s12_kernel(const float* __restrict__ Wh,
                                                  const float* __restrict__ a,
                                                  float* __restrict__ s1,
                                                  float* __restrict__ s2,
                                                  unsigned* __restrict__ maxslot, int n) {
    int wid = threadIdx.x >> 6, lane = threadIdx.x & 63;
    int r = blockIdx.x * 4 + wid;
    if (r >= n) return;
    float2 wh = *(const float2*)(Wh + (size_t)r * FD + 2 * lane);
    float2 a1 = *(const float2*)(a + 2 * lane);
    float2 a2 = *(const float2*)(a + FD + 2 * lane);
    float p1 = fmaf(wh.x, a1.x, wh.y * a1.y);
    float p2 = fmaf(wh.x, a2.x, wh.y * a2.y);
#pragma unroll
    for (int d = 1; d < 64; d <<= 1) {
        p1 += __shfl_xor(p1, d, 64);
        p2 += __shfl_xor(p2, d, 64);
    }
    if (lane == 0) {
        s1[r] = p1;
        s2[r] = p2;
        atomicMax(&maxslot[0], fenc(p1));
        atomicMax(&maxslot[1], fenc(p2));
    }
}

// ---- pass A: coarse bucket histogram (bucket = row >> 7), LDS-staged ----
__global__ __launch_bounds__(256) void bhist_kernel(const int* __restrict__ ei,
                                                    int* __restrict__ bhist,
                                                    int e_cnt, int nb) {
    __shared__ int h[NBMAX];
    int t = threadIdx.x;
    for (int i = t; i < NBMAX; i += 256) h[i] = 0;
    __syncthreads();
    int base = blockIdx.x * CH1;
    int m = min(CH1, e_cnt - base);
    for (int idx = t; idx < m; idx += 256) {
        int r = ei[base + idx];
        atomicAdd(&h[r >> 7], 1);
    }
    __syncthreads();
    for (int i = t; i < nb; i += 256)
        if (h[i]) atomicAdd(&bhist[i], h[i]);
}

// ---- scan bucket counts -> bstart / bcursor; also rowptr[n]=E ----
__global__ __launch_bounds__(512) void bscan_kernel(const int* __restrict__ bhist,
                                                    int* __restrict__ bstart,
                                                    int* __restrict__ bcursor,
                                                    int* __restrict__ rowptr,
                                                    int nb, int n, int e_cnt) {
    __shared__ int sc[512];
    int t = threadIdx.x;
    int v = (t < nb) ? bhist[t] : 0;
    sc[t] = v;
    __syncthreads();
    for (int off = 1; off < 512; off <<= 1) {
        int u = (t >= off) ? sc[t - off] : 0;
        __syncthreads();
        sc[t] += u;
        __syncthreads();
    }
    if (t < nb) {
        int ex = sc[t] - v;
        bstart[t] = ex;
        bcursor[t] = ex;
    }
    if (t == 0) { bstart[nb] = e_cnt; rowptr[n] = e_cnt; }
}

// ---- pass 1: LDS-staged binning into coarse buckets (contiguous writes) ----
__global__ __launch_bounds__(512) void bin_kernel(const int* __restrict__ ei,
                                                  int* __restrict__ bcursor,
                                                  unsigned* __restrict__ ebuf,
                                                  int e_cnt, int nb) {
    __shared__ int cnt[NBMAX];
    __shared__ int ex[NBMAX];
    __shared__ int gbase[NBMAX];
    __shared__ unsigned stage[CH1];
    int t = threadIdx.x;
    cnt[t] = 0;
    __syncthreads();
    int base = blockIdx.x * CH1;
    int m = min(CH1, e_cnt - base);

    unsigned pack[4];
    int rank[4], bkt[4];
    int nk = 0;
#pragma unroll
    for (int k = 0; k < 4; ++k) {
        int idx = t + k * 512;
        if (idx < m) {
            int e = base + idx;
            int r = ei[e];
            int c = ei[e_cnt + e];
            unsigned p = ((unsigned)r << 16) | (unsigned)c;
            int b = r >> 7;
            pack[nk] = p;
            bkt[nk] = b;
            rank[nk] = atomicAdd(&cnt[b], 1);
            ++nk;
        }
    }
    __syncthreads();
    int v = cnt[t];
    ex[t] = v;
    __syncthreads();
    for (int off = 1; off < 512; off <<= 1) {
        int u = (t >= off) ? ex[t - off] : 0;
        __syncthreads();
        ex[t] += u;
        __syncthreads();
    }
    int excl = ex[t] - v;   // exclusive prefix for bucket t
    if (t < nb && v > 0) gbase[t] = atomicAdd(&bcursor[t], v);
    __syncthreads();
    ex[t] = excl;
    __syncthreads();
    for (int k = 0; k < nk; ++k) stage[ex[bkt[k]] + rank[k]] = pack[k];
    __syncthreads();
    for (int s = t; s < m; s += 512) {
        unsigned p = stage[s];
        int b = p >> 23;                  // == (p>>16)>>7
        ebuf[gbase[b] + (s - ex[b])] = p;
    }
}

// ---- pass 2: per-bucket scatter into final CSR + rowptr (XCD-local writes) ----
__global__ __launch_bounds__(256) void scatter_kernel(const unsigned* __restrict__ ebuf,
                                                      const int* __restrict__ bstart,
                                                      int* __restrict__ rowptr,
                                                      int* __restrict__ csr_col,
                                                      int n) {
    __shared__ int cnt[128];
    __shared__ int ex[128];
    int b = blockIdx.x;
    int t = threadIdx.x;
    int row0 = b << 7;
    int nr = min(128, n - row0);
    int start = bstart[b];
    int m = bstart[b + 1] - start;
    if (t < 128) cnt[t] = 0;
    __syncthreads();
    for (int i = t; i < m; i += 256) {
        unsigned p = ebuf[start + i];
        atomicAdd(&cnt[(p >> 16) & 127], 1);
    }
    __syncthreads();
    int v = (t < 128) ? cnt[t] : 0;
    if (t < 128) ex[t] = v;
    __syncthreads();
    for (int off = 1; off < 128; off <<= 1) {
        int u = (t < 128 && t >= off) ? ex[t - off] : 0;
        __syncthreads();
        if (t < 128) ex[t] += u;
        __syncthreads();
    }
    int excl = (t < 128) ? (ex[t] - v) : 0;
    if (t < nr) rowptr[row0 + t] = start + excl;
    __syncthreads();
    if (t < 128) { ex[t] = excl; cnt[t] = 0; }
    __syncthreads();
    for (int i = t; i < m; i += 256) {
        unsigned p = ebuf[start + i];
        int lr = (p >> 16) & 127;
        int rk = atomicAdd(&cnt[lr], 1);
        csr_col[start + ex[lr] + rk] = (int)(p & 0xFFFFu);
    }
}

// ---- per-node softmax + weighted gather-aggregate + elu (one wave/node) ----
__global__ __launch_bounds__(256) void agg_kernel(const int* __restrict__ rowptr,
                                                  const int* __restrict__ csr_col,
                                                  const float* __restrict__ s1,
                                                  const float* __restrict__ s2,
                                                  const float* __restrict__ Wh,
                                                  const unsigned* __restrict__ maxslot,
                                                  float* __restrict__ out, int n) {
    int wid = threadIdx.x >> 6, lane = threadIdx.x & 63;
    int node = blockIdx.x * 4 + wid;
    if (node >= n) return;
    float M = fdec(maxslot[0]) + fdec(maxslot[1]);
    M = (M >= 0.f) ? M : 0.2f * M;      // leaky(upper bound) >= true max score
    int start = rowptr[node], end = rowptr[node + 1];
    float s1n = s1[node];

    // pass 1: sum of exp (lane-parallel over edges)
    float psum = 0.f;
    for (int j = start + lane; j < end; j += 64) {
        int c = csr_col[j];
        float sv = s1n + s2[c];
        float le = (sv >= 0.f) ? sv : 0.2f * sv;
        psum += expf(le - M);
    }
#pragma unroll
    for (int d = 1; d < 64; d <<= 1) psum += __shfl_xor(psum, d, 64);
    float inv = 1.0f / (psum + 1e-10f);

    // pass 2: half-wave per edge, float4 per lane over feature dim
    int half = lane >> 5, fl = lane & 31;
    float4 acc = make_float4(0.f, 0.f, 0.f, 0.f);
    for (int j = start + half; j < end; j += 2) {
        int c = csr_col[j];
        float sv = s1n + s2[c];
        float le = (sv >= 0.f) ? sv : 0.2f * sv;
        float w = expf(le - M) * inv;
        float4 wh = ((const float4*)(Wh + (size_t)c * FD))[fl];
        acc.x = fmaf(w, wh.x, acc.x);
        acc.y = fmaf(w, wh.y, acc.y);
        acc.z = fmaf(w, wh.z, acc.z);
        acc.w = fmaf(w, wh.w, acc.w);
    }
    acc.x += __shfl_xor(acc.x, 32, 64);
    acc.y += __shfl_xor(acc.y, 32, 64);
    acc.z += __shfl_xor(acc.z, 32, 64);
    acc.w += __shfl_xor(acc.w, 32, 64);
    if (half == 0) {
        float4 r;
        r.x = (acc.x > 0.f) ? acc.x : expm1f(acc.x);
        r.y = (acc.y > 0.f) ? acc.y : expm1f(acc.y);
        r.z = (acc.z > 0.f) ? acc.z : expm1f(acc.z);
        r.w = (acc.w > 0.f) ? acc.w : expm1f(acc.w);
        ((float4*)(out + (size_t)node * FD))[fl] = r;
    }
}

extern "C" void kernel_launch(void* const* d_in, const int* in_sizes, int n_in,
                              void* d_out, int out_size, void* d_ws, size_t ws_size,
                              hipStream_t stream) {
    const float* h = (const float*)d_in[0];
    const int* ei  = (const int*)d_in[1];
    const float* W = (const float*)d_in[2];
    const float* a = (const float*)d_in[3];
    float* out = (float*)d_out;
    int n = in_sizes[0] / FD;   // 50000
    int e = in_sizes[1] / 2;    // 800000
    int nb = (n + 127) >> 7;    // 391 coarse buckets (requires n <= 65536)

    char* ws = (char*)d_ws;
    size_t off = 0;
    auto alloc = [&](size_t bytes) -> void* {
        void* p = ws + off;
        off += bytes;
        off = (off + 255) & ~(size_t)255;
        return p;
    };
    float*    Wh      = (float*)alloc((size_t)n * FD * sizeof(float));
    float*    s1      = (float*)alloc((size_t)n * sizeof(float));
    float*    s2      = (float*)alloc((size_t)n * sizeof(float));
    int*      bhist   = (int*)alloc((size_t)NBMAX * sizeof(int));
    int*      bstart  = (int*)alloc((size_t)(NBMAX + 1) * sizeof(int));
    int*      bcursor = (int*)alloc((size_t)NBMAX * sizeof(int));
    unsigned* ebuf    = (unsigned*)alloc((size_t)e * sizeof(unsigned));
    int*      rowptr  = (int*)alloc((size_t)(n + 1) * sizeof(int));
    int*      csr_col = (int*)alloc((size_t)e * sizeof(int));
    unsigned* maxslot = (unsigned*)alloc(2 * sizeof(unsigned));

    int eblocks = (e + CH1 - 1) / CH1;   // 391

    init_kernel<<<1, 512, 0, stream>>>(bhist, maxslot);
    gemm_kernel<<<(n + 15) / 16, 256, 0, stream>>>(h, W, Wh, n);
    bhist_kernel<<<eblocks, 256, 0, stream>>>(ei, bhist, e, nb);
    s12_kernel<<<(n + 3) / 4, 256, 0, stream>>>(Wh, a, s1, s2, maxslot, n);
    bscan_kernel<<<1, 512, 0, stream>>>(bhist, bstart, bcursor, rowptr, nb, n, e);
    bin_kernel<<<eblocks, 512, 0, stream>>>(ei, bcursor, ebuf, e, nb);
    scatter_kernel<<<nb, 256, 0, stream>>>(ebuf, bstart, rowptr, csr_col, n);
    agg_kernel<<<(n + 3) / 4, 256, 0, stream>>>(rowptr, csr_col, s1, s2, Wh, maxslot, out, n);
}

// Round 3
// 245.097 us; speedup vs baseline: 5.6092x; 5.6092x over previous
//
#include <hip/hip_runtime.h>

constexpr int FD = 128;
constexpr int NBMAX = 512;   // max coarse buckets (rows/128); n<=65536
constexpr int CH1 = 2048;    // edges per binning block

// ---- monotone float<->uint encoding for atomic max over floats ----
__device__ __forceinline__ unsigned fenc(float f) {
    unsigned u = __float_as_uint(f);
    return (u & 0x80000000u) ? ~u : (u | 0x80000000u);
}
__device__ __forceinline__ float fdec(unsigned e) {
    return (e & 0x80000000u) ? __uint_as_float(e & 0x7fffffffu)
                             : __uint_as_float(~e);
}

// ---- zero bucket histogram, init max slots ----
__global__ __launch_bounds__(512) void init_kernel(int* __restrict__ bhist,
                                                   unsigned* __restrict__ maxslot) {
    int t = threadIdx.x;
    bhist[t] = 0;                          // NBMAX entries
    if (t < 2) maxslot[t] = 0x007FFFFFu;   // fenc(-inf)
}

// ---- Wh = h @ W^T  (fp32 vector ALU; 16 rows/block, thread = one out column) ----
__global__ __launch_bounds__(256) void gemm_kernel(const float* __restrict__ h,
                                                   const float* __restrict__ W,
                                                   float* __restrict__ Wh, int n) {
    __shared__ float hs[16 * FD];  // 8 KB
    int tid = threadIdx.x;
    int rbase = blockIdx.x * 16;

    {
        const float4* h4 = (const float4*)(h + (size_t)rbase * FD);
        float4* hs4 = (float4*)hs;
        int r0 = rbase + (tid >> 5);
        int r1 = rbase + ((tid + 256) >> 5);
        hs4[tid]       = (r0 < n) ? h4[tid]       : make_float4(0.f, 0.f, 0.f, 0.f);
        hs4[tid + 256] = (r1 < n) ? h4[tid + 256] : make_float4(0.f, 0.f, 0.f, 0.f);
    }
    __syncthreads();

    int j = tid & 127;
    int g = tid >> 7;
    float acc[8] = {0.f, 0.f, 0.f, 0.f, 0.f, 0.f, 0.f, 0.f};
    const float4* W4 = (const float4*)(W + (size_t)j * FD);

#pragma unroll 4
    for (int k4 = 0; k4 < 32; ++k4) {
        float4 w = W4[k4];
#pragma unroll
        for (int rr = 0; rr < 8; ++rr) {
            float4 hv = ((const float4*)(hs + (g * 8 + rr) * FD))[k4];
            acc[rr] = fmaf(w.x, hv.x, acc[rr]);
            acc[rr] = fmaf(w.y, hv.y, acc[rr]);
            acc[rr] = fmaf(w.z, hv.z, acc[rr]);
            acc[rr] = fmaf(w.w, hv.w, acc[rr]);
        }
    }
#pragma unroll
    for (int rr = 0; rr < 8; ++rr) {
        int r = rbase + g * 8 + rr;
        if (r < n) Wh[(size_t)r * FD + j] = acc[rr];
    }
}

// ---- s1/s2 per row (one wave per row, NO global atomics) ----
__global__ __launch_bounds__(256) void s12_kernel(const float* __restrict__ Wh,
                                                  const float* __restrict__ a,
                                                  float* __restrict__ s1,
                                                  float* __restrict__ s2, int n) {
    int wid = threadIdx.x >> 6, lane = threadIdx.x & 63;
    int r = blockIdx.x * 4 + wid;
    if (r >= n) return;
    float2 wh = *(const float2*)(Wh + (size_t)r * FD + 2 * lane);
    float2 a1 = *(const float2*)(a + 2 * lane);
    float2 a2 = *(const float2*)(a + FD + 2 * lane);
    float p1 = fmaf(wh.x, a1.x, wh.y * a1.y);
    float p2 = fmaf(wh.x, a2.x, wh.y * a2.y);
#pragma unroll
    for (int d = 1; d < 64; d <<= 1) {
        p1 += __shfl_xor(p1, d, 64);
        p2 += __shfl_xor(p2, d, 64);
    }
    if (lane == 0) { s1[r] = p1; s2[r] = p2; }
}

// ---- grid-stride max-reduce of s1/s2 -> maxslot (2 atomics per block) ----
__global__ __launch_bounds__(256) void smax_kernel(const float* __restrict__ s1,
                                                   const float* __restrict__ s2,
                                                   unsigned* __restrict__ maxslot, int n) {
    __shared__ float m1s[4], m2s[4];
    int t = threadIdx.x, lane = t & 63, wid = t >> 6;
    float m1 = -3.0e38f, m2 = -3.0e38f;
    for (int i = blockIdx.x * 256 + t; i < n; i += gridDim.x * 256) {
        m1 = fmaxf(m1, s1[i]);
        m2 = fmaxf(m2, s2[i]);
    }
#pragma unroll
    for (int d = 1; d < 64; d <<= 1) {
        m1 = fmaxf(m1, __shfl_xor(m1, d, 64));
        m2 = fmaxf(m2, __shfl_xor(m2, d, 64));
    }
    if (lane == 0) { m1s[wid] = m1; m2s[wid] = m2; }
    __syncthreads();
    if (t == 0) {
        m1 = fmaxf(fmaxf(m1s[0], m1s[1]), fmaxf(m1s[2], m1s[3]));
        m2 = fmaxf(fmaxf(m2s[0], m2s[1]), fmaxf(m2s[2], m2s[3]));
        atomicMax(&maxslot[0], fenc(m1));
        atomicMax(&maxslot[1], fenc(m2));
    }
}

// ---- pass A: coarse bucket histogram (bucket = row >> 7), LDS-staged ----
__global__ __launch_bounds__(256) void bhist_kernel(const int* __restrict__ ei,
                                                    int* __restrict__ bhist,
                                                    int e_cnt, int nb) {
    __shared__ int h[NBMAX];
    int t = threadIdx.x;
    for (int i = t; i < NBMAX; i += 256) h[i] = 0;
    __syncthreads();
    int base = blockIdx.x * CH1;
    int m = min(CH1, e_cnt - base);
    for (int idx = t; idx < m; idx += 256) {
        int r = ei[base + idx];
        atomicAdd(&h[r >> 7], 1);
    }
    __syncthreads();
    for (int i = t; i < nb; i += 256)
        if (h[i]) atomicAdd(&bhist[i], h[i]);
}

// ---- scan bucket counts -> bstart / bcursor; also rowptr[n]=E ----
__global__ __launch_bounds__(512) void bscan_kernel(const int* __restrict__ bhist,
                                                    int* __restrict__ bstart,
                                                    int* __restrict__ bcursor,
                                                    int* __restrict__ rowptr,
                                                    int nb, int n, int e_cnt) {
    __shared__ int sc[512];
    int t = threadIdx.x;
    int v = (t < nb) ? bhist[t] : 0;
    sc[t] = v;
    __syncthreads();
    for (int off = 1; off < 512; off <<= 1) {
        int u = (t >= off) ? sc[t - off] : 0;
        __syncthreads();
        sc[t] += u;
        __syncthreads();
    }
    if (t < nb) {
        int ex = sc[t] - v;
        bstart[t] = ex;
        bcursor[t] = ex;
    }
    if (t == 0) { bstart[nb] = e_cnt; rowptr[n] = e_cnt; }
}

// ---- pass 1: LDS-staged binning into coarse buckets (contiguous writes) ----
__global__ __launch_bounds__(512) void bin_kernel(const int* __restrict__ ei,
                                                  int* __restrict__ bcursor,
                                                  unsigned* __restrict__ ebuf,
                                                  int e_cnt, int nb) {
    __shared__ int cnt[NBMAX];
    __shared__ int ex[NBMAX];
    __shared__ int gbase[NBMAX];
    __shared__ unsigned stage[CH1];
    int t = threadIdx.x;
    cnt[t] = 0;
    __syncthreads();
    int base = blockIdx.x * CH1;
    int m = min(CH1, e_cnt - base);

    unsigned pack[4];
    int rank[4], bkt[4];
    int nk = 0;
#pragma unroll
    for (int k = 0; k < 4; ++k) {
        int idx = t + k * 512;
        if (idx < m) {
            int e = base + idx;
            int r = ei[e];
            int c = ei[e_cnt + e];
            unsigned p = ((unsigned)r << 16) | (unsigned)c;
            int b = r >> 7;
            pack[nk] = p;
            bkt[nk] = b;
            rank[nk] = atomicAdd(&cnt[b], 1);
            ++nk;
        }
    }
    __syncthreads();
    int v = cnt[t];
    ex[t] = v;
    __syncthreads();
    for (int off = 1; off < 512; off <<= 1) {
        int u = (t >= off) ? ex[t - off] : 0;
        __syncthreads();
        ex[t] += u;
        __syncthreads();
    }
    int excl = ex[t] - v;   // exclusive prefix for bucket t
    if (t < nb && v > 0) gbase[t] = atomicAdd(&bcursor[t], v);
    __syncthreads();
    ex[t] = excl;
    __syncthreads();
    for (int k = 0; k < nk; ++k) stage[ex[bkt[k]] + rank[k]] = pack[k];
    __syncthreads();
    for (int s = t; s < m; s += 512) {
        unsigned p = stage[s];
        int b = p >> 23;                  // == (p>>16)>>7
        ebuf[gbase[b] + (s - ex[b])] = p;
    }
}

// ---- pass 2: per-bucket scatter into final CSR + rowptr (XCD-local writes) ----
__global__ __launch_bounds__(256) void scatter_kernel(const unsigned* __restrict__ ebuf,
                                                      const int* __restrict__ bstart,
                                                      int* __restrict__ rowptr,
                                                      int* __restrict__ csr_col,
                                                      int n) {
    __shared__ int cnt[128];
    __shared__ int ex[128];
    int b = blockIdx.x;
    int t = threadIdx.x;
    int row0 = b << 7;
    int nr = min(128, n - row0);
    int start = bstart[b];
    int m = bstart[b + 1] - start;
    if (t < 128) cnt[t] = 0;
    __syncthreads();
    for (int i = t; i < m; i += 256) {
        unsigned p = ebuf[start + i];
        atomicAdd(&cnt[(p >> 16) & 127], 1);
    }
    __syncthreads();
    int v = (t < 128) ? cnt[t] : 0;
    if (t < 128) ex[t] = v;
    __syncthreads();
    for (int off = 1; off < 128; off <<= 1) {
        int u = (t < 128 && t >= off) ? ex[t - off] : 0;
        __syncthreads();
        if (t < 128) ex[t] += u;
        __syncthreads();
    }
    int excl = (t < 128) ? (ex[t] - v) : 0;
    if (t < nr) rowptr[row0 + t] = start + excl;
    __syncthreads();
    if (t < 128) { ex[t] = excl; cnt[t] = 0; }
    __syncthreads();
    for (int i = t; i < m; i += 256) {
        unsigned p = ebuf[start + i];
        int lr = (p >> 16) & 127;
        int rk = atomicAdd(&cnt[lr], 1);
        csr_col[start + ex[lr] + rk] = (int)(p & 0xFFFFu);
    }
}

// ---- per-node softmax + weighted gather-aggregate + elu (one wave/node) ----
__global__ __launch_bounds__(256) void agg_kernel(const int* __restrict__ rowptr,
                                                  const int* __restrict__ csr_col,
                                                  const float* __restrict__ s1,
                                                  const float* __restrict__ s2,
                                                  const float* __restrict__ Wh,
                                                  const unsigned* __restrict__ maxslot,
                                                  float* __restrict__ out, int n) {
    int wid = threadIdx.x >> 6, lane = threadIdx.x & 63;
    int node = blockIdx.x * 4 + wid;
    if (node >= n) return;
    float M = fdec(maxslot[0]) + fdec(maxslot[1]);
    M = (M >= 0.f) ? M : 0.2f * M;      // leaky(upper bound) >= true max score
    int start = rowptr[node], end = rowptr[node + 1];
    float s1n = s1[node];

    // pass 1: sum of exp (lane-parallel over edges)
    float psum = 0.f;
    for (int j = start + lane; j < end; j += 64) {
        int c = csr_col[j];
        float sv = s1n + s2[c];
        float le = (sv >= 0.f) ? sv : 0.2f * sv;
        psum += expf(le - M);
    }
#pragma unroll
    for (int d = 1; d < 64; d <<= 1) psum += __shfl_xor(psum, d, 64);
    float inv = 1.0f / (psum + 1e-10f);

    // pass 2: half-wave per edge, float4 per lane over feature dim
    int half = lane >> 5, fl = lane & 31;
    float4 acc = make_float4(0.f, 0.f, 0.f, 0.f);
    for (int j = start + half; j < end; j += 2) {
        int c = csr_col[j];
        float sv = s1n + s2[c];
        float le = (sv >= 0.f) ? sv : 0.2f * sv;
        float w = expf(le - M) * inv;
        float4 wh = ((const float4*)(Wh + (size_t)c * FD))[fl];
        acc.x = fmaf(w, wh.x, acc.x);
        acc.y = fmaf(w, wh.y, acc.y);
        acc.z = fmaf(w, wh.z, acc.z);
        acc.w = fmaf(w, wh.w, acc.w);
    }
    acc.x += __shfl_xor(acc.x, 32, 64);
    acc.y += __shfl_xor(acc.y, 32, 64);
    acc.z += __shfl_xor(acc.z, 32, 64);
    acc.w += __shfl_xor(acc.w, 32, 64);
    if (half == 0) {
        float4 r;
        r.x = (acc.x > 0.f) ? acc.x : expm1f(acc.x);
        r.y = (acc.y > 0.f) ? acc.y : expm1f(acc.y);
        r.z = (acc.z > 0.f) ? acc.z : expm1f(acc.z);
        r.w = (acc.w > 0.f) ? acc.w : expm1f(acc.w);
        ((float4*)(out + (size_t)node * FD))[fl] = r;
    }
}

extern "C" void kernel_launch(void* const* d_in, const int* in_sizes, int n_in,
                              void* d_out, int out_size, void* d_ws, size_t ws_size,
                              hipStream_t stream) {
    const float* h = (const float*)d_in[0];
    const int* ei  = (const int*)d_in[1];
    const float* W = (const float*)d_in[2];
    const float* a = (const float*)d_in[3];
    float* out = (float*)d_out;
    int n = in_sizes[0] / FD;   // 50000
    int e = in_sizes[1] / 2;    // 800000
    int nb = (n + 127) >> 7;    // 391 coarse buckets (requires n <= 65536)

    char* ws = (char*)d_ws;
    size_t off = 0;
    auto alloc = [&](size_t bytes) -> void* {
        void* p = ws + off;
        off += bytes;
        off = (off + 255) & ~(size_t)255;
        return p;
    };
    float*    Wh      = (float*)alloc((size_t)n * FD * sizeof(float));
    float*    s1      = (float*)alloc((size_t)n * sizeof(float));
    float*    s2      = (float*)alloc((size_t)n * sizeof(float));
    int*      bhist   = (int*)alloc((size_t)NBMAX * sizeof(int));
    int*      bstart  = (int*)alloc((size_t)(NBMAX + 1) * sizeof(int));
    int*      bcursor = (int*)alloc((size_t)NBMAX * sizeof(int));
    unsigned* ebuf    = (unsigned*)alloc((size_t)e * sizeof(unsigned));
    int*      rowptr  = (int*)alloc((size_t)(n + 1) * sizeof(int));
    int*      csr_col = (int*)alloc((size_t)e * sizeof(int));
    unsigned* maxslot = (unsigned*)alloc(2 * sizeof(unsigned));

    int eblocks = (e + CH1 - 1) / CH1;   // 391

    init_kernel<<<1, 512, 0, stream>>>(bhist, maxslot);
    gemm_kernel<<<(n + 15) / 16, 256, 0, stream>>>(h, W, Wh, n);
    bhist_kernel<<<eblocks, 256, 0, stream>>>(ei, bhist, e, nb);
    s12_kernel<<<(n + 3) / 4, 256, 0, stream>>>(Wh, a, s1, s2, n);
    smax_kernel<<<104, 256, 0, stream>>>(s1, s2, maxslot, n);
    bscan_kernel<<<1, 512, 0, stream>>>(bhist, bstart, bcursor, rowptr, nb, n, e);
    bin_kernel<<<eblocks, 512, 0, stream>>>(ei, bcursor, ebuf, e, nb);
    scatter_kernel<<<nb, 256, 0, stream>>>(ebuf, bstart, rowptr, csr_col, n);
    agg_kernel<<<(n + 3) / 4, 256, 0, stream>>>(rowptr, csr_col, s1, s2, Wh, maxslot, out, n);
}

// Round 4
// 190.954 us; speedup vs baseline: 7.1996x; 1.2835x over previous
//
#include <hip/hip_runtime.h>

constexpr int FD = 128;
constexpr int NBMAX = 512;   // max coarse buckets (rows/128); n<=65536
constexpr int CH1 = 2048;    // edges per binning block

// ---- monotone float<->uint encoding for atomic max over floats ----
__device__ __forceinline__ unsigned fenc(float f) {
    unsigned u = __float_as_uint(f);
    return (u & 0x80000000u) ? ~u : (u | 0x80000000u);
}
__device__ __forceinline__ float fdec(unsigned e) {
    return (e & 0x80000000u) ? __uint_as_float(e & 0x7fffffffu)
                             : __uint_as_float(~e);
}

// RNE pack of two fp32 -> (lo=even feat, hi=odd feat) bf16 pair
__device__ __forceinline__ unsigned bpack(float x, float y) {
    unsigned ux = __float_as_uint(x); ux += 0x7FFFu + ((ux >> 16) & 1u);
    unsigned uy = __float_as_uint(y); uy += 0x7FFFu + ((uy >> 16) & 1u);
    return (ux >> 16) | (uy & 0xFFFF0000u);
}

// ---- zero bucket histogram, init max slots ----
__global__ __launch_bounds__(512) void init_kernel(int* __restrict__ bhist,
                                                   unsigned* __restrict__ maxslot) {
    int t = threadIdx.x;
    bhist[t] = 0;
    if (t < 2) maxslot[t] = 0x007FFFFFu;   // fenc(-inf)
}

// ---- W_t[k][j] = W[j][k]  (64 KB, trivial) ----
__global__ __launch_bounds__(128) void wt_kernel(const float* __restrict__ W,
                                                 float* __restrict__ Wt) {
    int j = blockIdx.x, k = threadIdx.x;           // read W row j coalesced
    Wt[(size_t)k * FD + j] = W[(size_t)j * FD + k];
}

// ---- fused GEMM: Whb(bf16) = h @ W^T ; s1/s2 epilogue ----
// block = 256 thr, tile 32 rows x 128 cols, thread = 4 rows x 4 cols outer product
__global__ __launch_bounds__(256) void gemm_kernel(const float* __restrict__ h,
                                                   const float* __restrict__ Wt,
                                                   const float* __restrict__ a,
                                                   unsigned* __restrict__ Whb,
                                                   float* __restrict__ s1,
                                                   float* __restrict__ s2, int n) {
    __shared__ float hs[FD * 36];  // h_t[k][r], row stride 36 dwords, XOR-swizzled groups
    int tid = threadIdx.x;
    int rbase = blockIdx.x * 32;

    // stage h transposed: thread q -> row-group rgrp=q>>5 (4 rows), k4=q&31 (4 ks)
    {
        int rgrp = tid >> 5, k4 = tid & 31;
        float4 v[4];
#pragma unroll
        for (int i = 0; i < 4; ++i) {
            int gr = rbase + 4 * rgrp + i;
            v[i] = (gr < n) ? ((const float4*)h)[(size_t)gr * 32 + k4]
                            : make_float4(0.f, 0.f, 0.f, 0.f);
        }
#pragma unroll
        for (int kk = 0; kk < 4; ++kk) {
            int k = 4 * k4 + kk;
            float4 w;
            w.x = (&v[0].x)[kk]; w.y = (&v[1].x)[kk];
            w.z = (&v[2].x)[kk]; w.w = (&v[3].x)[kk];
            *(float4*)(hs + k * 36 + 4 * (rgrp ^ (k & 7))) = w;
        }
    }
    __syncthreads();

    int tc = tid & 31, tr = tid >> 5;   // tc: 32 col-groups, tr: 8 row-groups
    float acc[4][4] = {};
    const float4* Wt4 = (const float4*)Wt;

#pragma unroll 4
    for (int k = 0; k < FD; ++k) {
        float4 w = Wt4[(size_t)k * 32 + tc];                       // cols 4tc..4tc+3
        float4 hv = *(const float4*)(hs + k * 36 + 4 * (tr ^ (k & 7)));  // rows 4tr..4tr+3
#pragma unroll
        for (int i = 0; i < 4; ++i) {
            float hvi = (&hv.x)[i];
            acc[i][0] = fmaf(hvi, w.x, acc[i][0]);
            acc[i][1] = fmaf(hvi, w.y, acc[i][1]);
            acc[i][2] = fmaf(hvi, w.z, acc[i][2]);
            acc[i][3] = fmaf(hvi, w.w, acc[i][3]);
        }
    }

    // epilogue A: bf16 Wh rows (cols 4tc..4tc+3 per thread)
#pragma unroll
    for (int i = 0; i < 4; ++i) {
        int r = rbase + 4 * tr + i;
        if (r < n) {
            uint2 p;
            p.x = bpack(acc[i][0], acc[i][1]);
            p.y = bpack(acc[i][2], acc[i][3]);
            *(uint2*)(Whb + (size_t)r * 64 + 2 * tc) = p;
        }
    }

    // epilogue B: s1/s2 = Wh . a1/a2, reduced across the 32 tc lanes
    float4 a1v = ((const float4*)a)[tc];
    float4 a2v = ((const float4*)a)[32 + tc];
    float p1[4], p2[4];
#pragma unroll
    for (int i = 0; i < 4; ++i) {
        p1[i] = acc[i][0] * a1v.x + acc[i][1] * a1v.y + acc[i][2] * a1v.z + acc[i][3] * a1v.w;
        p2[i] = acc[i][0] * a2v.x + acc[i][1] * a2v.y + acc[i][2] * a2v.z + acc[i][3] * a2v.w;
    }
#pragma unroll
    for (int d = 1; d < 32; d <<= 1) {
#pragma unroll
        for (int i = 0; i < 4; ++i) {
            p1[i] += __shfl_xor(p1[i], d, 64);
            p2[i] += __shfl_xor(p2[i], d, 64);
        }
    }
    if (tc == 0) {
#pragma unroll
        for (int i = 0; i < 4; ++i) {
            int r = rbase + 4 * tr + i;
            if (r < n) { s1[r] = p1[i]; s2[r] = p2[i]; }
        }
    }
}

// ---- grid-stride max-reduce of s1/s2 -> maxslot (2 atomics per block) ----
__global__ __launch_bounds__(256) void smax_kernel(const float* __restrict__ s1,
                                                   const float* __restrict__ s2,
                                                   unsigned* __restrict__ maxslot, int n) {
    __shared__ float m1s[4], m2s[4];
    int t = threadIdx.x, lane = t & 63, wid = t >> 6;
    float m1 = -3.0e38f, m2 = -3.0e38f;
    for (int i = blockIdx.x * 256 + t; i < n; i += gridDim.x * 256) {
        m1 = fmaxf(m1, s1[i]);
        m2 = fmaxf(m2, s2[i]);
    }
#pragma unroll
    for (int d = 1; d < 64; d <<= 1) {
        m1 = fmaxf(m1, __shfl_xor(m1, d, 64));
        m2 = fmaxf(m2, __shfl_xor(m2, d, 64));
    }
    if (lane == 0) { m1s[wid] = m1; m2s[wid] = m2; }
    __syncthreads();
    if (t == 0) {
        m1 = fmaxf(fmaxf(m1s[0], m1s[1]), fmaxf(m1s[2], m1s[3]));
        m2 = fmaxf(fmaxf(m2s[0], m2s[1]), fmaxf(m2s[2], m2s[3]));
        atomicMax(&maxslot[0], fenc(m1));
        atomicMax(&maxslot[1], fenc(m2));
    }
}

// ---- pass A: coarse bucket histogram (bucket = row >> 7), LDS-staged ----
__global__ __launch_bounds__(256) void bhist_kernel(const int* __restrict__ ei,
                                                    int* __restrict__ bhist,
                                                    int e_cnt, int nb) {
    __shared__ int h[NBMAX];
    int t = threadIdx.x;
    for (int i = t; i < NBMAX; i += 256) h[i] = 0;
    __syncthreads();
    int base = blockIdx.x * CH1;
    int m = min(CH1, e_cnt - base);
    for (int idx = t; idx < m; idx += 256) {
        int r = ei[base + idx];
        atomicAdd(&h[r >> 7], 1);
    }
    __syncthreads();
    for (int i = t; i < nb; i += 256)
        if (h[i]) atomicAdd(&bhist[i], h[i]);
}

// ---- scan bucket counts -> bstart / bcursor; also rowptr[n]=E ----
__global__ __launch_bounds__(512) void bscan_kernel(const int* __restrict__ bhist,
                                                    int* __restrict__ bstart,
                                                    int* __restrict__ bcursor,
                                                    int* __restrict__ rowptr,
                                                    int nb, int n, int e_cnt) {
    __shared__ int sc[512];
    int t = threadIdx.x;
    int v = (t < nb) ? bhist[t] : 0;
    sc[t] = v;
    __syncthreads();
    for (int off = 1; off < 512; off <<= 1) {
        int u = (t >= off) ? sc[t - off] : 0;
        __syncthreads();
        sc[t] += u;
        __syncthreads();
    }
    if (t < nb) {
        int ex = sc[t] - v;
        bstart[t] = ex;
        bcursor[t] = ex;
    }
    if (t == 0) { bstart[nb] = e_cnt; rowptr[n] = e_cnt; }
}

// ---- pass 1: LDS-staged binning into coarse buckets (contiguous writes) ----
__global__ __launch_bounds__(512) void bin_kernel(const int* __restrict__ ei,
                                                  int* __restrict__ bcursor,
                                                  unsigned* __restrict__ ebuf,
                                                  int e_cnt, int nb) {
    __shared__ int cnt[NBMAX];
    __shared__ int ex[NBMAX];
    __shared__ int gbase[NBMAX];
    __shared__ unsigned stage[CH1];
    int t = threadIdx.x;
    cnt[t] = 0;
    __syncthreads();
    int base = blockIdx.x * CH1;
    int m = min(CH1, e_cnt - base);

    unsigned pack[4];
    int rank[4], bkt[4];
    int nk = 0;
#pragma unroll
    for (int k = 0; k < 4; ++k) {
        int idx = t + k * 512;
        if (idx < m) {
            int e = base + idx;
            int r = ei[e];
            int c = ei[e_cnt + e];
            unsigned p = ((unsigned)r << 16) | (unsigned)c;
            int b = r >> 7;
            pack[nk] = p;
            bkt[nk] = b;
            rank[nk] = atomicAdd(&cnt[b], 1);
            ++nk;
        }
    }
    __syncthreads();
    int v = cnt[t];
    ex[t] = v;
    __syncthreads();
    for (int off = 1; off < 512; off <<= 1) {
        int u = (t >= off) ? ex[t - off] : 0;
        __syncthreads();
        ex[t] += u;
        __syncthreads();
    }
    int excl = ex[t] - v;
    if (t < nb && v > 0) gbase[t] = atomicAdd(&bcursor[t], v);
    __syncthreads();
    ex[t] = excl;
    __syncthreads();
    for (int k = 0; k < nk; ++k) stage[ex[bkt[k]] + rank[k]] = pack[k];
    __syncthreads();
    for (int s = t; s < m; s += 512) {
        unsigned p = stage[s];
        int b = p >> 23;
        ebuf[gbase[b] + (s - ex[b])] = p;
    }
}

// ---- pass 2: per-bucket scatter into final CSR + rowptr (XCD-local writes) ----
__global__ __launch_bounds__(256) void scatter_kernel(const unsigned* __restrict__ ebuf,
                                                      const int* __restrict__ bstart,
                                                      int* __restrict__ rowptr,
                                                      int* __restrict__ csr_col,
                                                      int n) {
    __shared__ int cnt[128];
    __shared__ int ex[128];
    int b = blockIdx.x;
    int t = threadIdx.x;
    int row0 = b << 7;
    int nr = min(128, n - row0);
    int start = bstart[b];
    int m = bstart[b + 1] - start;
    if (t < 128) cnt[t] = 0;
    __syncthreads();
    for (int i = t; i < m; i += 256) {
        unsigned p = ebuf[start + i];
        atomicAdd(&cnt[(p >> 16) & 127], 1);
    }
    __syncthreads();
    int v = (t < 128) ? cnt[t] : 0;
    if (t < 128) ex[t] = v;
    __syncthreads();
    for (int off = 1; off < 128; off <<= 1) {
        int u = (t < 128 && t >= off) ? ex[t - off] : 0;
        __syncthreads();
        if (t < 128) ex[t] += u;
        __syncthreads();
    }
    int excl = (t < 128) ? (ex[t] - v) : 0;
    if (t < nr) rowptr[row0 + t] = start + excl;
    __syncthreads();
    if (t < 128) { ex[t] = excl; cnt[t] = 0; }
    __syncthreads();
    for (int i = t; i < m; i += 256) {
        unsigned p = ebuf[start + i];
        int lr = (p >> 16) & 127;
        int rk = atomicAdd(&cnt[lr], 1);
        csr_col[start + ex[lr] + rk] = (int)(p & 0xFFFFu);
    }
}

// ---- per-node softmax + bf16 gather-aggregate + elu (one wave/node) ----
__global__ __launch_bounds__(256) void agg_kernel(const int* __restrict__ rowptr,
                                                  const int* __restrict__ csr_col,
                                                  const float* __restrict__ s1,
                                                  const float* __restrict__ s2,
                                                  const unsigned* __restrict__ Whb,
                                                  const unsigned* __restrict__ maxslot,
                                                  float* __restrict__ out, int n) {
    __shared__ float expv[4][64];
    __shared__ int colv[4][64];
    int w = threadIdx.x >> 6, l = threadIdx.x & 63;
    int node = blockIdx.x * 4 + w;
    if (node >= n) return;
    float M = fdec(maxslot[0]) + fdec(maxslot[1]);
    M = (M >= 0.f) ? M : 0.2f * M;   // leaky(upper bound) >= true max score
    int start = rowptr[node], end = rowptr[node + 1];
    int deg = end - start;
    float s1n = s1[node];

    float2 acc = make_float2(0.f, 0.f);

    if (deg <= 64) {
        // single chunk: exp -> LDS once, no recompute
        int idx = start + l;
        float ev = 0.f; int c = 0;
        if (idx < end) {
            c = csr_col[idx];
            float sv = s1n + s2[c];
            float le = (sv >= 0.f) ? sv : 0.2f * sv;
            ev = expf(le - M);
        }
        expv[w][l] = ev;
        colv[w][l] = c;
        float psum = ev;
#pragma unroll
        for (int d = 1; d < 64; d <<= 1) psum += __shfl_xor(psum, d, 64);
        float inv = 1.0f / (psum + 1e-10f);
        for (int j = 0; j < deg; ++j) {
            float alpha = expv[w][j] * inv;        // LDS broadcast
            int cc = colv[w][j];
            unsigned b2 = Whb[(size_t)cc * 64 + l];  // 2 bf16 feats, 256B/row coalesced
            acc.x = fmaf(alpha, __uint_as_float(b2 << 16), acc.x);
            acc.y = fmaf(alpha, __uint_as_float(b2 & 0xFFFF0000u), acc.y);
        }
    } else {
        // rare: chunked two-phase
        float psum = 0.f;
        for (int c0 = start; c0 < end; c0 += 64) {
            int idx = c0 + l;
            if (idx < end) {
                int c = csr_col[idx];
                float sv = s1n + s2[c];
                float le = (sv >= 0.f) ? sv : 0.2f * sv;
                psum += expf(le - M);
            }
        }
#pragma unroll
        for (int d = 1; d < 64; d <<= 1) psum += __shfl_xor(psum, d, 64);
        float inv = 1.0f / (psum + 1e-10f);
        for (int c0 = start; c0 < end; c0 += 64) {
            int idx = c0 + l;
            float ev = 0.f; int c = 0;
            if (idx < end) {
                c = csr_col[idx];
                float sv = s1n + s2[c];
                float le = (sv >= 0.f) ? sv : 0.2f * sv;
                ev = expf(le - M);
            }
            expv[w][l] = ev;
            colv[w][l] = c;
            int mc = min(64, end - c0);
            for (int j = 0; j < mc; ++j) {
                float alpha = expv[w][j] * inv;
                int cc = colv[w][j];
                unsigned b2 = Whb[(size_t)cc * 64 + l];
                acc.x = fmaf(alpha, __uint_as_float(b2 << 16), acc.x);
                acc.y = fmaf(alpha, __uint_as_float(b2 & 0xFFFF0000u), acc.y);
            }
        }
    }

    float2 r;
    r.x = (acc.x > 0.f) ? acc.x : expm1f(acc.x);
    r.y = (acc.y > 0.f) ? acc.y : expm1f(acc.y);
    *(float2*)(out + (size_t)node * FD + 2 * l) = r;
}

extern "C" void kernel_launch(void* const* d_in, const int* in_sizes, int n_in,
                              void* d_out, int out_size, void* d_ws, size_t ws_size,
                              hipStream_t stream) {
    const float* h = (const float*)d_in[0];
    const int* ei  = (const int*)d_in[1];
    const float* W = (const float*)d_in[2];
    const float* a = (const float*)d_in[3];
    float* out = (float*)d_out;
    int n = in_sizes[0] / FD;   // 50000
    int e = in_sizes[1] / 2;    // 800000
    int nb = (n + 127) >> 7;    // coarse buckets (requires n <= 65536)

    char* ws = (char*)d_ws;
    size_t off = 0;
    auto alloc = [&](size_t bytes) -> void* {
        void* p = ws + off;
        off += bytes;
        off = (off + 255) & ~(size_t)255;
        return p;
    };
    unsigned* Whb     = (unsigned*)alloc((size_t)n * 64 * sizeof(unsigned));  // bf16 Wh
    float*    Wt      = (float*)alloc((size_t)FD * FD * sizeof(float));
    float*    s1      = (float*)alloc((size_t)n * sizeof(float));
    float*    s2      = (float*)alloc((size_t)n * sizeof(float));
    int*      bhist   = (int*)alloc((size_t)NBMAX * sizeof(int));
    int*      bstart  = (int*)alloc((size_t)(NBMAX + 1) * sizeof(int));
    int*      bcursor = (int*)alloc((size_t)NBMAX * sizeof(int));
    unsigned* ebuf    = (unsigned*)alloc((size_t)e * sizeof(unsigned));
    int*      rowptr  = (int*)alloc((size_t)(n + 1) * sizeof(int));
    int*      csr_col = (int*)alloc((size_t)e * sizeof(int));
    unsigned* maxslot = (unsigned*)alloc(2 * sizeof(unsigned));

    int eblocks = (e + CH1 - 1) / CH1;

    init_kernel<<<1, 512, 0, stream>>>(bhist, maxslot);
    wt_kernel<<<FD, FD, 0, stream>>>(W, Wt);
    bhist_kernel<<<eblocks, 256, 0, stream>>>(ei, bhist, e, nb);
    gemm_kernel<<<(n + 31) / 32, 256, 0, stream>>>(h, Wt, a, Whb, s1, s2, n);
    smax_kernel<<<104, 256, 0, stream>>>(s1, s2, maxslot, n);
    bscan_kernel<<<1, 512, 0, stream>>>(bhist, bstart, bcursor, rowptr, nb, n, e);
    bin_kernel<<<eblocks, 512, 0, stream>>>(ei, bcursor, ebuf, e, nb);
    scatter_kernel<<<nb, 256, 0, stream>>>(ebuf, bstart, rowptr, csr_col, n);
    agg_kernel<<<(n + 3) / 4, 256, 0, stream>>>(rowptr, csr_col, s1, s2, Whb, maxslot, out, n);
}